// Round 9
// baseline (319.706 us; speedup 1.0000x reference)
//
#include <hip/hip_runtime.h>
#include <math.h>

#define HW 192
#define OW 182          // 192 - 11 + 1
#define NPIX (OW*OW)
#define NTILE 8
#define SSIM_C1 0.01f   // (0.01*10)^2
#define SSIM_C2 0.09f   // (0.03*10)^2

// normalized gaussian, ws=11 sigma=1.5 (symmetric)
#define Gk0 0.0010283835f
#define Gk1 0.0075987615f
#define Gk2 0.0360007700f
#define Gk3 0.1093608000f
#define Gk4 0.2130055400f
#define Gk5 0.2660117000f

#define EBPAD 212       // f-row stride in floats: 16B-aligned, 212%32=20

typedef float v2f __attribute__((ext_vector_type(2)));
typedef float v4f __attribute__((ext_vector_type(4)));

__device__ __forceinline__ v2f vfma(float w, v2f a, v2f b) {
    return __builtin_elementwise_fma((v2f){w, w}, a, b);
}
__device__ __forceinline__ v2f vfma2(v2f w, v2f a, v2f b) {
    return __builtin_elementwise_fma(w, a, b);
}
__device__ __forceinline__ v2f sp2(float s) { return (v2f){s, s}; }

__device__ __forceinline__ void dgauss(float g[11]) {
    float s = 0.f;
#pragma unroll
    for (int i = 0; i < 11; ++i) {
        float d = (float)(i - 5);
        g[i] = expf(-(d * d) / 4.5f);
        s += g[i];
    }
    float inv = 1.f / s;
#pragma unroll
    for (int i = 0; i < 11; ++i) g[i] *= inv;
}

// ---------------------------------------------------------------------------
// Kernel 1: mu_f and (sig_f + C2) for the 24 feature images (grid=24*14, 256t)
// ---------------------------------------------------------------------------
__global__ __launch_bounds__(256) void muf_kernel(const float* __restrict__ xf,
                                                  float* __restrict__ muf,
                                                  float* __restrict__ sigc2f) {
    const int tile = blockIdx.x % 14;
    const int img  = blockIdx.x / 14;
    const int r0   = tile * 13;

    __shared__ float raw[23][192];
    __shared__ float hb[2][23][184];

    float g[11]; dgauss(g);
    const int t = threadIdx.x;
    const float* src = xf + (size_t)img * HW * HW;

    for (int i = t; i < 23 * 192; i += 256) {
        int rr = i / 192, col = i - rr * 192;
        raw[rr][col] = src[(r0 + rr) * HW + col];
    }
    __syncthreads();

    for (int i = t; i < 23 * OW; i += 256) {
        int rr = i / OW, co = i - rr * OW;
        float a0 = 0.f, a1 = 0.f;
#pragma unroll
        for (int k = 0; k < 11; ++k) {
            float v = raw[rr][co + k];
            float w = g[k];
            a0 += w * v;
            a1 += w * v * v;
        }
        hb[0][rr][co] = a0;
        hb[1][rr][co] = a1;
    }
    __syncthreads();

    for (int i = t; i < 13 * OW; i += 256) {
        int rr = i / OW, co = i - rr * OW;
        float m = 0.f, s2 = 0.f;
#pragma unroll
        for (int k = 0; k < 11; ++k) {
            float w = g[k];
            m  += w * hb[0][rr + k][co];
            s2 += w * hb[1][rr + k][co];
        }
        size_t o = (size_t)img * NPIX + (size_t)(r0 + rr) * OW + co;
        muf[o]    = m;
        sigc2f[o] = s2 - m * m + SSIM_C2;
    }
}

// ---------------------------------------------------------------------------
// Kernel 2: fused SSIM. One (b,c,row-tile) per block; grid = 8*64*8 = 4096.
// 4 rows per iteration, 1 barrier. vstep keyed by col t; hblur keyed by
// (row r = t/48, q = t%48): each act thread computes 4 cols of one row via
// 4 aligned ds_read_b128 (16-float window, NAMED scalars — no local array)
// + packed coeff-table accumulation. 8-slot ring, f-rows padded to 212.
// ---------------------------------------------------------------------------
__global__ __launch_bounds__(192, 3) void ssim_kernel(const float* __restrict__ x,
                                                      const float* __restrict__ xf,
                                                      const float* __restrict__ muf,
                                                      const float* __restrict__ sigc2f,
                                                      float* __restrict__ part) {
    const float G[11] = {Gk0,Gk1,Gk2,Gk3,Gk4,Gk5,Gk4,Gk3,Gk2,Gk1,Gk0};
    // T[i] = (coeff of w[i] in out0, coeff of w[i] in out1)
    v2f T[12];
    T[0] = (v2f){G[0], 0.f};
#pragma unroll
    for (int i = 1; i <= 10; ++i) T[i] = (v2f){G[i], G[i - 1]};
    T[11] = (v2f){0.f, G[10]};

    const int blk  = blockIdx.x;
    const int c    = blk & 63;
    const int tile = (blk >> 6) & 7;
    const int b    = blk >> 9;

    const int out0  = (tile * 182) >> 3;
    const int out1  = ((tile + 1) * 182) >> 3;
    const int n_out = out1 - out0;              // 22 or 23

    const int t  = threadIdx.x;
    const int r  = t / 48;                      // hblur row within group, 0..3
    const int q  = t - 48 * r;                  // 0..47
    const int c0 = 4 * q;                       // first output col
    const bool act  = (q < 46);
    const bool p2ok = (c0 + 2 < OW);            // q <= 44

    const float* xp  = x  + ((size_t)(b * 64 + c)) * HW * HW + (size_t)out0 * HW + t;
    const float* fp0 = xf + ((size_t)(b * 3 + 0)) * HW * HW + (size_t)out0 * HW + t;
    const float* fp1 = fp0 + HW * HW;
    const float* fp2 = fp1 + HW * HW;

    const float* mp = muf    + (size_t)(b * 3) * NPIX + (size_t)(out0 + r) * OW + c0;
    const float* cp = sigc2f + (size_t)(b * 3) * NPIX + (size_t)(out0 + r) * OW + c0;

    __shared__ __align__(16) float eb[8][5][EBPAD];
    __shared__ float red[3][3];

    v2f P01[10], P23[10];
    float P4[10];
#pragma unroll
    for (int j = 0; j < 10; ++j) { P01[j] = (v2f){0.f,0.f}; P23[j] = (v2f){0.f,0.f}; P4[j] = 0.f; }

    v2f A0 = {0.f,0.f}, A1 = {0.f,0.f}, A2 = {0.f,0.f};

    v2f eE01, eE23; float eE4;

    auto vstep = [&](float xv, float a0, float a1, float a2, bool emit) {
        v2f v01 = {xv, xv * xv};
        v2f v23 = {xv * a0, xv * a1};
        float v4 = xv * a2;
        if (emit) {
            eE01 = vfma(G[10], v01, P01[0]);
            eE23 = vfma(G[10], v23, P23[0]);
            eE4  = fmaf(G[10], v4, P4[0]);
        }
#pragma unroll
        for (int j = 0; j < 9; ++j) {
            P01[j] = vfma(G[9 - j], v01, P01[j + 1]);
            P23[j] = vfma(G[9 - j], v23, P23[j + 1]);
            P4[j]  = fmaf(G[9 - j], v4, P4[j + 1]);
        }
        P01[9] = G[0] * v01;
        P23[9] = G[0] * v23;
        P4[9]  = G[0] * v4;
    };

    auto ssim2 = [&](const v2f mux, const v2f mux2, const v2f sigc,
                     const v2f mf, const v2f cc, const v2f h, v2f& A) {
        v2f t1  = mf * mux;
        v2f sfx = h - t1;
        v2f v1s = vfma(2.f, sfx, (v2f){SSIM_C2, SSIM_C2});
        v2f n1  = vfma(2.f, t1, (v2f){SSIM_C1, SSIM_C1});
        v2f num = n1 * v1s;
        v2f qd  = vfma2(mf, mf, (v2f){SSIM_C1, SSIM_C1});
        v2f den = (qd + mux2) * (cc + sigc);
        v2f inv = {__builtin_amdgcn_rcpf(den.x), __builtin_amdgcn_rcpf(den.y)};
        A = vfma2(num, inv, A);
    };

    auto store_e = [&](int slot) {
        eb[slot][0][t] = eE01.x; eb[slot][1][t] = eE01.y;
        eb[slot][2][t] = eE23.x; eb[slot][3][t] = eE23.y;
        eb[slot][4][t] = eE4;
    };

    // ---- prologue: input rows 0..9, no emission ----
#pragma unroll 1
    for (int rr = 0; rr < 10; rr += 2) {
        float xA0 = xp[0],  a00 = fp0[0],  a10 = fp1[0],  a20 = fp2[0];
        float xB0 = xp[HW], b00 = fp0[HW], b10 = fp1[HW], b20 = fp2[HW];
        xp += 2 * HW; fp0 += 2 * HW; fp1 += 2 * HW; fp2 += 2 * HW;
        vstep(xA0, a00, a10, a20, false);
        vstep(xB0, b00, b10, b20, false);
    }

    const int ngrp = (n_out + 3) >> 2;   // 6

    // ---- preload group-0 stream rows (input rows 10..13; always valid) ----
    float cx[4], cf0[4], cf1[4], cf2[4];
#pragma unroll
    for (int j = 0; j < 4; ++j) {
        cx[j]  = xp[j * HW];  cf0[j] = fp0[j * HW];
        cf1[j] = fp1[j * HW]; cf2[j] = fp2[j * HW];
    }
    xp += 4 * HW; fp0 += 4 * HW; fp1 += 4 * HW; fp2 += 4 * HW;

    // ---- main loop: 4 rows per iteration, 1 barrier ----
#pragma unroll 1
    for (int p = 0; p < ngrp; ++p) {
        // (1) prefetch next group's stream rows (clamped to last stream row)
        float nx[4], nf0[4], nf1[4], nf2[4];
        {
            const int rb = 4 * p + 4;
#pragma unroll
            for (int j = 0; j < 4; ++j) {
                const int off = (((rb + j) < n_out) ? j : (n_out - 1 - rb)) * HW;
                nx[j]  = xp[off];  nf0[j] = fp0[off];
                nf1[j] = fp1[off]; nf2[j] = fp2[off];
            }
            xp += 4 * HW; fp0 += 4 * HW; fp1 += 4 * HW; fp2 += 4 * HW;
        }

        const bool row_ok = act && (4 * p + r < n_out);

        // (2) pair-0 moments, prefetched before the barrier
        v2f mfa0, mfa1, mfa2, cca0, cca1, cca2;
        if (row_ok) {
            mfa0 = *(const v2f*)(mp);
            mfa1 = *(const v2f*)(mp + NPIX);
            mfa2 = *(const v2f*)(mp + 2 * NPIX);
            cca0 = *(const v2f*)(cp);
            cca1 = *(const v2f*)(cp + NPIX);
            cca2 = *(const v2f*)(cp + 2 * NPIX);
        }

        // (3) vstep + store the current 4 rows
#pragma unroll
        for (int j = 0; j < 4; ++j) {
            vstep(cx[j], cf0[j], cf1[j], cf2[j], true);
            store_e((4 * p + j) & 7);
        }
        __syncthreads();

        // (4) rotate stream regs
#pragma unroll
        for (int j = 0; j < 4; ++j) {
            cx[j] = nx[j]; cf0[j] = nf0[j]; cf1[j] = nf1[j]; cf2[j] = nf2[j];
        }

        // (5) hblur (4 cols via b128 window reads, NAMED scalars) + ssim
        if (row_ok) {
            const int slot = (4 * p + r) & 7;
            v2f h01[5], h23[5];
#pragma unroll
            for (int f = 0; f < 5; ++f) {
                const float* ep = &eb[slot][f][0] + c0;
                v4f w0 = *(const v4f*)(ep);
                v4f w1 = *(const v4f*)(ep + 4);
                v4f w2 = *(const v4f*)(ep + 8);
                v4f w3 = *(const v4f*)(ep + 12);

                v2f o01 = T[0] * sp2(w0.x);
                o01 = vfma2(T[1],  sp2(w0.y), o01);
                o01 = vfma2(T[2],  sp2(w0.z), o01);
                o01 = vfma2(T[3],  sp2(w0.w), o01);
                o01 = vfma2(T[4],  sp2(w1.x), o01);
                o01 = vfma2(T[5],  sp2(w1.y), o01);
                o01 = vfma2(T[6],  sp2(w1.z), o01);
                o01 = vfma2(T[7],  sp2(w1.w), o01);
                o01 = vfma2(T[8],  sp2(w2.x), o01);
                o01 = vfma2(T[9],  sp2(w2.y), o01);
                o01 = vfma2(T[10], sp2(w2.z), o01);
                o01 = vfma2(T[11], sp2(w2.w), o01);

                v2f o23 = T[0] * sp2(w0.z);
                o23 = vfma2(T[1],  sp2(w0.w), o23);
                o23 = vfma2(T[2],  sp2(w1.x), o23);
                o23 = vfma2(T[3],  sp2(w1.y), o23);
                o23 = vfma2(T[4],  sp2(w1.z), o23);
                o23 = vfma2(T[5],  sp2(w1.w), o23);
                o23 = vfma2(T[6],  sp2(w2.x), o23);
                o23 = vfma2(T[7],  sp2(w2.y), o23);
                o23 = vfma2(T[8],  sp2(w2.z), o23);
                o23 = vfma2(T[9],  sp2(w2.w), o23);
                o23 = vfma2(T[10], sp2(w3.x), o23);
                o23 = vfma2(T[11], sp2(w3.y), o23);

                h01[f] = o01; h23[f] = o23;
            }

            // pair-1 moments issued here, consumed after pair-0 ssim
            v2f mfb0, mfb1, mfb2, ccb0, ccb1, ccb2;
            if (p2ok) {
                mfb0 = *(const v2f*)(mp + 2);
                mfb1 = *(const v2f*)(mp + NPIX + 2);
                mfb2 = *(const v2f*)(mp + 2 * NPIX + 2);
                ccb0 = *(const v2f*)(cp + 2);
                ccb1 = *(const v2f*)(cp + NPIX + 2);
                ccb2 = *(const v2f*)(cp + 2 * NPIX + 2);
            }

            {
                const v2f mux  = h01[0];
                const v2f mux2 = mux * mux;
                const v2f sigc = h01[1] - mux2;
                ssim2(mux, mux2, sigc, mfa0, cca0, h01[2], A0);
                ssim2(mux, mux2, sigc, mfa1, cca1, h01[3], A1);
                ssim2(mux, mux2, sigc, mfa2, cca2, h01[4], A2);
            }
            if (p2ok) {
                const v2f mux  = h23[0];
                const v2f mux2 = mux * mux;
                const v2f sigc = h23[1] - mux2;
                ssim2(mux, mux2, sigc, mfb0, ccb0, h23[2], A0);
                ssim2(mux, mux2, sigc, mfb1, ccb1, h23[3], A1);
                ssim2(mux, mux2, sigc, mfb2, ccb2, h23[4], A2);
            }
        }

        mp += 4 * OW; cp += 4 * OW;
    }

    // ---- block reduction (3 waves) ----
    float acc0 = A0.x + A0.y;
    float acc1 = A1.x + A1.y;
    float acc2 = A2.x + A2.y;
#pragma unroll
    for (int off = 32; off > 0; off >>= 1) {
        acc0 += __shfl_down(acc0, off);
        acc1 += __shfl_down(acc1, off);
        acc2 += __shfl_down(acc2, off);
    }
    const int wid = t >> 6, lane = t & 63;
    if (lane == 0) { red[0][wid] = acc0; red[1][wid] = acc1; red[2][wid] = acc2; }
    __syncthreads();
    if (t == 0) {
        const size_t o = (size_t)tile * 1536 + (size_t)b * 192;
        part[o +   0 + c] = red[0][0] + red[0][1] + red[0][2];
        part[o +  64 + c] = red[1][0] + red[1][1] + red[1][2];
        part[o + 128 + c] = red[2][0] + red[2][1] + red[2][2];
    }
}

// ---------------------------------------------------------------------------
// Kernel 3: combine tile partials -> ssim_info, then conv gate + MLP + sigmoid
// ---------------------------------------------------------------------------
__global__ __launch_bounds__(64) void gate_kernel(const float* __restrict__ part,
                                                  const float* __restrict__ sw,
                                                  const float* __restrict__ W1,
                                                  const float* __restrict__ b1,
                                                  const float* __restrict__ W2,
                                                  const float* __restrict__ b2,
                                                  float* __restrict__ out,
                                                  float* __restrict__ out_ssim) {
    const int b = blockIdx.x;
    const int c = threadIdx.x;   // 0..63

    __shared__ float s[3][64];
    __shared__ float h0[64];
    __shared__ float h1[64];

    const float inv = 1.f / (float)NPIX;
#pragma unroll
    for (int f = 0; f < 3; ++f) {
        const int i = b * 192 + f * 64 + c;
        float v = 0.f;
#pragma unroll
        for (int k = 0; k < NTILE; ++k) v += part[i + k * 1536];
        v *= inv;
        s[f][c] = v;
        out_ssim[i] = v;
    }
    __syncthreads();

    float a = 0.f;
#pragma unroll
    for (int f = 0; f < 3; ++f)
#pragma unroll
        for (int i = 0; i < 3; ++i) {
            int cc = c - 1 + i;
            if (cc >= 0 && cc < 64) a += sw[f * 3 + i] * s[f][cc];
        }
    h0[c] = fmaxf(a, 0.f);
    __syncthreads();

    float a1 = b1[c];
    for (int j = 0; j < 64; ++j) a1 += W1[c * 64 + j] * h0[j];
    h1[c] = fmaxf(a1, 0.f);
    __syncthreads();

    float a2 = b2[c];
    for (int j = 0; j < 64; ++j) a2 += W2[c * 64 + j] * h1[j];
    out[b * 64 + c] = 1.f / (1.f + expf(-a2));
}

// ---------------------------------------------------------------------------
extern "C" void kernel_launch(void* const* d_in, const int* in_sizes, int n_in,
                              void* d_out, int out_size, void* d_ws, size_t ws_size,
                              hipStream_t stream) {
    const float* x  = (const float*)d_in[0];
    const float* xf = (const float*)d_in[1];
    const float* sw = (const float*)d_in[2];
    const float* W1 = (const float*)d_in[3];
    const float* b1 = (const float*)d_in[4];
    const float* W2 = (const float*)d_in[5];
    const float* b2 = (const float*)d_in[6];
    float* out = (float*)d_out;

    float* muf  = (float*)d_ws;            // [24][182*182]
    float* sigf = muf + 24 * NPIX;         // [24][182*182]  (sig + C2)
    float* part = sigf + 24 * NPIX;        // [NTILE][8][3][64]

    muf_kernel <<<24 * 14,        256, 0, stream>>>(xf, muf, sigf);
    ssim_kernel<<<8 * 64 * NTILE, 192, 0, stream>>>(x, xf, muf, sigf, part);
    gate_kernel<<<8,               64, 0, stream>>>(part, sw, W1, b1, W2, b2, out, out + 512);
}

// Round 10
// 119.021 us; speedup vs baseline: 2.6861x; 2.6861x over previous
//
#include <hip/hip_runtime.h>
#include <math.h>

#define HW 192
#define OW 182          // 192 - 11 + 1
#define NPIX (OW*OW)
#define NTILE 8
#define SSIM_C1 0.01f   // (0.01*10)^2
#define SSIM_C2 0.09f   // (0.03*10)^2

// normalized gaussian, ws=11 sigma=1.5 (symmetric)
#define Gk0 0.0010283835f
#define Gk1 0.0075987615f
#define Gk2 0.0360007700f
#define Gk3 0.1093608000f
#define Gk4 0.2130055400f
#define Gk5 0.2660117000f

typedef float v2f __attribute__((ext_vector_type(2)));

__device__ __forceinline__ v2f vfma(float w, v2f a, v2f b) {
    return __builtin_elementwise_fma((v2f){w, w}, a, b);
}
__device__ __forceinline__ v2f vfma2(v2f w, v2f a, v2f b) {
    return __builtin_elementwise_fma(w, a, b);
}

__device__ __forceinline__ void dgauss(float g[11]) {
    float s = 0.f;
#pragma unroll
    for (int i = 0; i < 11; ++i) {
        float d = (float)(i - 5);
        g[i] = expf(-(d * d) / 4.5f);
        s += g[i];
    }
    float inv = 1.f / s;
#pragma unroll
    for (int i = 0; i < 11; ++i) g[i] *= inv;
}

// ---------------------------------------------------------------------------
// Kernel 1: mu_f and (sig_f + C2) for the 24 feature images (grid=24*14, 256t)
// ---------------------------------------------------------------------------
__global__ __launch_bounds__(256) void muf_kernel(const float* __restrict__ xf,
                                                  float* __restrict__ muf,
                                                  float* __restrict__ sigc2f) {
    const int tile = blockIdx.x % 14;
    const int img  = blockIdx.x / 14;
    const int r0   = tile * 13;

    __shared__ float raw[23][192];
    __shared__ float hb[2][23][184];

    float g[11]; dgauss(g);
    const int t = threadIdx.x;
    const float* src = xf + (size_t)img * HW * HW;

    for (int i = t; i < 23 * 192; i += 256) {
        int rr = i / 192, col = i - rr * 192;
        raw[rr][col] = src[(r0 + rr) * HW + col];
    }
    __syncthreads();

    for (int i = t; i < 23 * OW; i += 256) {
        int rr = i / OW, co = i - rr * OW;
        float a0 = 0.f, a1 = 0.f;
#pragma unroll
        for (int k = 0; k < 11; ++k) {
            float v = raw[rr][co + k];
            float w = g[k];
            a0 += w * v;
            a1 += w * v * v;
        }
        hb[0][rr][co] = a0;
        hb[1][rr][co] = a1;
    }
    __syncthreads();

    for (int i = t; i < 13 * OW; i += 256) {
        int rr = i / OW, co = i - rr * OW;
        float m = 0.f, s2 = 0.f;
#pragma unroll
        for (int k = 0; k < 11; ++k) {
            float w = g[k];
            m  += w * hb[0][rr + k][co];
            s2 += w * hb[1][rr + k][co];
        }
        size_t o = (size_t)img * NPIX + (size_t)(r0 + rr) * OW + co;
        muf[o]    = m;
        sigc2f[o] = s2 - m * m + SSIM_C2;
    }
}

// ---------------------------------------------------------------------------
// Kernel 2: fused SSIM. One (b,c,row-tile) per block; grid = 8*64*8 = 4096.
// 4 output rows per iteration, ONE barrier (8-slot LDS ring). De-fattened:
// uniform-branch prefetch (no per-lane clamps in the steady state), phase-A
// moments loaded pre-barrier, phase-B moments post-barrier but well before
// use. Inner vstep/hblur identical to the proven r4/r7 dataflow.
// ---------------------------------------------------------------------------
__global__ __launch_bounds__(192, 3) void ssim_kernel(const float* __restrict__ x,
                                                      const float* __restrict__ xf,
                                                      const float* __restrict__ muf,
                                                      const float* __restrict__ sigc2f,
                                                      float* __restrict__ part) {
    const float G[11] = {Gk0,Gk1,Gk2,Gk3,Gk4,Gk5,Gk4,Gk3,Gk2,Gk1,Gk0};
    const v2f WA[6] = {{G[0],0.f},{G[2],G[1]},{G[4],G[3]},{G[6],G[5]},{G[8],G[7]},{G[10],G[9]}};
    const v2f WB[6] = {{G[1],G[0]},{G[3],G[2]},{G[5],G[4]},{G[7],G[6]},{G[9],G[8]},{0.f,G[10]}};

    const int blk  = blockIdx.x;
    const int c    = blk & 63;
    const int tile = (blk >> 6) & 7;
    const int b    = blk >> 9;

    const int out0  = (tile * 182) >> 3;
    const int out1  = ((tile + 1) * 182) >> 3;
    const int n_out = out1 - out0;              // 22 or 23

    const int t    = threadIdx.x;
    const int half = (t >= 96) ? 1 : 0;
    const int u    = half ? (t - 96) : t;
    const int cu   = 2 * u;
    const bool act = (u <= 90);

    const float* xp  = x  + ((size_t)(b * 64 + c)) * HW * HW + (size_t)out0 * HW + t;
    const float* fp0 = xf + ((size_t)(b * 3 + 0)) * HW * HW + (size_t)out0 * HW + t;
    const float* fp1 = fp0 + HW * HW;
    const float* fp2 = fp1 + HW * HW;

    const float* mp = muf    + (size_t)(b * 3) * NPIX + (size_t)(out0 + half) * OW + cu;
    const float* cp = sigc2f + (size_t)(b * 3) * NPIX + (size_t)(out0 + half) * OW + cu;

    __shared__ float eb[8][5][192];
    __shared__ float red[3][3];

    v2f P01[10], P23[10];
    float P4[10];
#pragma unroll
    for (int j = 0; j < 10; ++j) { P01[j] = (v2f){0.f,0.f}; P23[j] = (v2f){0.f,0.f}; P4[j] = 0.f; }

    v2f A0 = {0.f,0.f}, A1 = {0.f,0.f}, A2 = {0.f,0.f};

    v2f eE01, eE23; float eE4;

    auto vstep = [&](float xv, float a0, float a1, float a2, bool emit) {
        v2f v01 = {xv, xv * xv};
        v2f v23 = {xv * a0, xv * a1};
        float v4 = xv * a2;
        if (emit) {
            eE01 = vfma(G[10], v01, P01[0]);
            eE23 = vfma(G[10], v23, P23[0]);
            eE4  = fmaf(G[10], v4, P4[0]);
        }
#pragma unroll
        for (int j = 0; j < 9; ++j) {
            P01[j] = vfma(G[9 - j], v01, P01[j + 1]);
            P23[j] = vfma(G[9 - j], v23, P23[j + 1]);
            P4[j]  = fmaf(G[9 - j], v4, P4[j + 1]);
        }
        P01[9] = G[0] * v01;
        P23[9] = G[0] * v23;
        P4[9]  = G[0] * v4;
    };

    auto ssim2 = [&](const v2f mux, const v2f mux2, const v2f sigc,
                     const v2f mf, const v2f cc, const v2f h, v2f& A) {
        v2f t1  = mf * mux;
        v2f sfx = h - t1;
        v2f v1s = vfma(2.f, sfx, (v2f){SSIM_C2, SSIM_C2});
        v2f n1  = vfma(2.f, t1, (v2f){SSIM_C1, SSIM_C1});
        v2f num = n1 * v1s;
        v2f qd  = vfma2(mf, mf, (v2f){SSIM_C1, SSIM_C1});
        v2f den = (qd + mux2) * (cc + sigc);
        v2f inv = {__builtin_amdgcn_rcpf(den.x), __builtin_amdgcn_rcpf(den.y)};
        A = vfma2(num, inv, A);
    };

    auto store_e = [&](int slot) {
        eb[slot][0][t] = eE01.x; eb[slot][1][t] = eE01.y;
        eb[slot][2][t] = eE23.x; eb[slot][3][t] = eE23.y;
        eb[slot][4][t] = eE4;
    };

    // hblur + ssim for one slot with preloaded moments
    auto do_hb = [&](int slot, v2f mf0, v2f mf1, v2f mf2,
                               v2f cc0, v2f cc1, v2f cc2) {
        v2f hacc[5];
#pragma unroll
        for (int f = 0; f < 5; ++f) {
            const float* ep = &eb[slot][f][cu];
            v2f a = {0.f, 0.f};
#pragma unroll
            for (int m = 0; m < 6; ++m) {
                v2f rd = *(const v2f*)(ep + 2 * m);
                a = vfma2(WA[m], __builtin_shufflevector(rd, rd, 0, 0), a);
                a = vfma2(WB[m], __builtin_shufflevector(rd, rd, 1, 1), a);
            }
            hacc[f] = a;
        }
        const v2f mux  = hacc[0];
        const v2f mux2 = mux * mux;
        const v2f sigc = hacc[1] - mux2;
        ssim2(mux, mux2, sigc, mf0, cc0, hacc[2], A0);
        ssim2(mux, mux2, sigc, mf1, cc1, hacc[3], A1);
        ssim2(mux, mux2, sigc, mf2, cc2, hacc[4], A2);
    };

    // ---- prologue: input rows 0..9, no emission ----
#pragma unroll 1
    for (int rr = 0; rr < 10; rr += 2) {
        float xA0 = xp[0],  a00 = fp0[0],  a10 = fp1[0],  a20 = fp2[0];
        float xB0 = xp[HW], b00 = fp0[HW], b10 = fp1[HW], b20 = fp2[HW];
        xp += 2 * HW; fp0 += 2 * HW; fp1 += 2 * HW; fp2 += 2 * HW;
        vstep(xA0, a00, a10, a20, false);
        vstep(xB0, b00, b10, b20, false);
    }

    const int ngrp = (n_out + 3) >> 2;   // 6

    // ---- preload group-0 stream rows (input rows 10..13; always valid) ----
    float cx[4], cf0[4], cf1[4], cf2[4];
#pragma unroll
    for (int j = 0; j < 4; ++j) {
        cx[j]  = xp[j * HW];  cf0[j] = fp0[j * HW];
        cf1[j] = fp1[j * HW]; cf2[j] = fp2[j * HW];
    }
    xp += 4 * HW; fp0 += 4 * HW; fp1 += 4 * HW; fp2 += 4 * HW;

    // ---- main loop: 4 rows per iteration, 1 barrier ----
#pragma unroll 1
    for (int p = 0; p < ngrp; ++p) {
        // (1) prefetch next group's stream rows; uniform branch, clamp only
        //     in the last two iterations
        float nx[4], nf0[4], nf1[4], nf2[4];
        const int rb = 4 * p + 4;
        if (rb + 4 <= n_out) {
#pragma unroll
            for (int j = 0; j < 4; ++j) {
                nx[j]  = xp[j * HW];  nf0[j] = fp0[j * HW];
                nf1[j] = fp1[j * HW]; nf2[j] = fp2[j * HW];
            }
        } else {
#pragma unroll
            for (int j = 0; j < 4; ++j) {
                const int off = (((rb + j) < n_out) ? j : (n_out - 1 - rb)) * HW;
                nx[j]  = xp[off];  nf0[j] = fp0[off];
                nf1[j] = fp1[off]; nf2[j] = fp2[off];
            }
        }
        xp += 4 * HW; fp0 += 4 * HW; fp1 += 4 * HW; fp2 += 4 * HW;

        const bool okA = act;                                  // row 4p+half
        const bool okB = act && (4 * p + 2 + half < n_out);    // row 4p+2+half

        // (2) phase-A moments pre-barrier
        v2f mfa0, mfa1, mfa2, cca0, cca1, cca2;
        if (okA) {
            mfa0 = *(const v2f*)(mp);
            mfa1 = *(const v2f*)(mp + NPIX);
            mfa2 = *(const v2f*)(mp + 2 * NPIX);
            cca0 = *(const v2f*)(cp);
            cca1 = *(const v2f*)(cp + NPIX);
            cca2 = *(const v2f*)(cp + 2 * NPIX);
        }

        // (3) vstep + store the current 4 rows
#pragma unroll
        for (int j = 0; j < 4; ++j) {
            if (4 * p + j < n_out) {
                vstep(cx[j], cf0[j], cf1[j], cf2[j], true);
                store_e((4 * p + j) & 7);
            }
        }
        __syncthreads();

        // (4) phase-B moments issued early, consumed after phase A
        v2f mfb0, mfb1, mfb2, ccb0, ccb1, ccb2;
        if (okB) {
            mfb0 = *(const v2f*)(mp + 2 * OW);
            mfb1 = *(const v2f*)(mp + 2 * OW + NPIX);
            mfb2 = *(const v2f*)(mp + 2 * OW + 2 * NPIX);
            ccb0 = *(const v2f*)(cp + 2 * OW);
            ccb1 = *(const v2f*)(cp + 2 * OW + NPIX);
            ccb2 = *(const v2f*)(cp + 2 * OW + 2 * NPIX);
        }

        // (5) rotate stream regs
#pragma unroll
        for (int j = 0; j < 4; ++j) {
            cx[j] = nx[j]; cf0[j] = nf0[j]; cf1[j] = nf1[j]; cf2[j] = nf2[j];
        }

        // (6) hblur + ssim, two sub-phases
        if (okA) do_hb((4 * p + half) & 7, mfa0, mfa1, mfa2, cca0, cca1, cca2);
        if (okB) do_hb((4 * p + 2 + half) & 7, mfb0, mfb1, mfb2, ccb0, ccb1, ccb2);

        mp += 4 * OW; cp += 4 * OW;
    }

    // ---- block reduction (3 waves) ----
    float acc0 = A0.x + A0.y;
    float acc1 = A1.x + A1.y;
    float acc2 = A2.x + A2.y;
#pragma unroll
    for (int off = 32; off > 0; off >>= 1) {
        acc0 += __shfl_down(acc0, off);
        acc1 += __shfl_down(acc1, off);
        acc2 += __shfl_down(acc2, off);
    }
    const int wid = t >> 6, lane = t & 63;
    if (lane == 0) { red[0][wid] = acc0; red[1][wid] = acc1; red[2][wid] = acc2; }
    __syncthreads();
    if (t == 0) {
        const size_t o = (size_t)tile * 1536 + (size_t)b * 192;
        part[o +   0 + c] = red[0][0] + red[0][1] + red[0][2];
        part[o +  64 + c] = red[1][0] + red[1][1] + red[1][2];
        part[o + 128 + c] = red[2][0] + red[2][1] + red[2][2];
    }
}

// ---------------------------------------------------------------------------
// Kernel 3: combine tile partials -> ssim_info, then conv gate + MLP + sigmoid
// ---------------------------------------------------------------------------
__global__ __launch_bounds__(64) void gate_kernel(const float* __restrict__ part,
                                                  const float* __restrict__ sw,
                                                  const float* __restrict__ W1,
                                                  const float* __restrict__ b1,
                                                  const float* __restrict__ W2,
                                                  const float* __restrict__ b2,
                                                  float* __restrict__ out,
                                                  float* __restrict__ out_ssim) {
    const int b = blockIdx.x;
    const int c = threadIdx.x;   // 0..63

    __shared__ float s[3][64];
    __shared__ float h0[64];
    __shared__ float h1[64];

    const float inv = 1.f / (float)NPIX;
#pragma unroll
    for (int f = 0; f < 3; ++f) {
        const int i = b * 192 + f * 64 + c;
        float v = 0.f;
#pragma unroll
        for (int k = 0; k < NTILE; ++k) v += part[i + k * 1536];
        v *= inv;
        s[f][c] = v;
        out_ssim[i] = v;
    }
    __syncthreads();

    float a = 0.f;
#pragma unroll
    for (int f = 0; f < 3; ++f)
#pragma unroll
        for (int i = 0; i < 3; ++i) {
            int cc = c - 1 + i;
            if (cc >= 0 && cc < 64) a += sw[f * 3 + i] * s[f][cc];
        }
    h0[c] = fmaxf(a, 0.f);
    __syncthreads();

    float a1 = b1[c];
    for (int j = 0; j < 64; ++j) a1 += W1[c * 64 + j] * h0[j];
    h1[c] = fmaxf(a1, 0.f);
    __syncthreads();

    float a2 = b2[c];
    for (int j = 0; j < 64; ++j) a2 += W2[c * 64 + j] * h1[j];
    out[b * 64 + c] = 1.f / (1.f + expf(-a2));
}

// ---------------------------------------------------------------------------
extern "C" void kernel_launch(void* const* d_in, const int* in_sizes, int n_in,
                              void* d_out, int out_size, void* d_ws, size_t ws_size,
                              hipStream_t stream) {
    const float* x  = (const float*)d_in[0];
    const float* xf = (const float*)d_in[1];
    const float* sw = (const float*)d_in[2];
    const float* W1 = (const float*)d_in[3];
    const float* b1 = (const float*)d_in[4];
    const float* W2 = (const float*)d_in[5];
    const float* b2 = (const float*)d_in[6];
    float* out = (float*)d_out;

    float* muf  = (float*)d_ws;            // [24][182*182]
    float* sigf = muf + 24 * NPIX;         // [24][182*182]  (sig + C2)
    float* part = sigf + 24 * NPIX;        // [NTILE][8][3][64]

    muf_kernel <<<24 * 14,        256, 0, stream>>>(xf, muf, sigf);
    ssim_kernel<<<8 * 64 * NTILE, 192, 0, stream>>>(x, xf, muf, sigf, part);
    gate_kernel<<<8,               64, 0, stream>>>(part, sw, W1, b1, W2, b2, out, out + 512);
}

// Round 11
// 109.502 us; speedup vs baseline: 2.9196x; 1.0869x over previous
//
#include <hip/hip_runtime.h>
#include <math.h>

#define HW 192
#define OW 182          // 192 - 11 + 1
#define NPIX (OW*OW)
#define NTILE 8
#define SSIM_C1 0.01f   // (0.01*10)^2
#define SSIM_C2 0.09f   // (0.03*10)^2

// normalized gaussian, ws=11 sigma=1.5 (symmetric)
#define Gk0 0.0010283835f
#define Gk1 0.0075987615f
#define Gk2 0.0360007700f
#define Gk3 0.1093608000f
#define Gk4 0.2130055400f
#define Gk5 0.2660117000f

// LDS-only barrier: does NOT drain vmcnt, so in-flight global prefetch
// loads survive across it (HIP __syncthreads drains vmcnt(0) -> serializes
// the HBM stream every phase). lgkmcnt(0) preserves ds_write->ds_read order.
#define BAR_LDS() asm volatile("s_waitcnt lgkmcnt(0)\n\ts_barrier" ::: "memory")

typedef float v2f __attribute__((ext_vector_type(2)));

__device__ __forceinline__ v2f vfma(float w, v2f a, v2f b) {
    return __builtin_elementwise_fma((v2f){w, w}, a, b);
}
__device__ __forceinline__ v2f vfma2(v2f w, v2f a, v2f b) {
    return __builtin_elementwise_fma(w, a, b);
}

__device__ __forceinline__ void dgauss(float g[11]) {
    float s = 0.f;
#pragma unroll
    for (int i = 0; i < 11; ++i) {
        float d = (float)(i - 5);
        g[i] = expf(-(d * d) / 4.5f);
        s += g[i];
    }
    float inv = 1.f / s;
#pragma unroll
    for (int i = 0; i < 11; ++i) g[i] *= inv;
}

// ---------------------------------------------------------------------------
// Kernel 1: mu_f and (sig_f + C2) for the 24 feature images (grid=24*14, 256t)
// ---------------------------------------------------------------------------
__global__ __launch_bounds__(256) void muf_kernel(const float* __restrict__ xf,
                                                  float* __restrict__ muf,
                                                  float* __restrict__ sigc2f) {
    const int tile = blockIdx.x % 14;
    const int img  = blockIdx.x / 14;
    const int r0   = tile * 13;

    __shared__ float raw[23][192];
    __shared__ float hb[2][23][184];

    float g[11]; dgauss(g);
    const int t = threadIdx.x;
    const float* src = xf + (size_t)img * HW * HW;

    for (int i = t; i < 23 * 192; i += 256) {
        int rr = i / 192, col = i - rr * 192;
        raw[rr][col] = src[(r0 + rr) * HW + col];
    }
    __syncthreads();

    for (int i = t; i < 23 * OW; i += 256) {
        int rr = i / OW, co = i - rr * OW;
        float a0 = 0.f, a1 = 0.f;
#pragma unroll
        for (int k = 0; k < 11; ++k) {
            float v = raw[rr][co + k];
            float w = g[k];
            a0 += w * v;
            a1 += w * v * v;
        }
        hb[0][rr][co] = a0;
        hb[1][rr][co] = a1;
    }
    __syncthreads();

    for (int i = t; i < 13 * OW; i += 256) {
        int rr = i / OW, co = i - rr * OW;
        float m = 0.f, s2 = 0.f;
#pragma unroll
        for (int k = 0; k < 11; ++k) {
            float w = g[k];
            m  += w * hb[0][rr + k][co];
            s2 += w * hb[1][rr + k][co];
        }
        size_t o = (size_t)img * NPIX + (size_t)(r0 + rr) * OW + co;
        muf[o]    = m;
        sigc2f[o] = s2 - m * m + SSIM_C2;
    }
}

// ---------------------------------------------------------------------------
// Kernel 2: fused SSIM. One (b,c,row-tile) per block; grid = 8*64*8 = 4096.
// r4 structure exactly (2 rows/iter, depth-1 register prefetch, 4-slot ring)
// but with an LDS-only barrier so the global stream prefetch stays in
// flight across phases instead of being drained every iteration.
// ---------------------------------------------------------------------------
__global__ __launch_bounds__(192, 4) void ssim_kernel(const float* __restrict__ x,
                                                      const float* __restrict__ xf,
                                                      const float* __restrict__ muf,
                                                      const float* __restrict__ sigc2f,
                                                      float* __restrict__ part) {
    const float G[11] = {Gk0,Gk1,Gk2,Gk3,Gk4,Gk5,Gk4,Gk3,Gk2,Gk1,Gk0};
    const v2f WA[6] = {{G[0],0.f},{G[2],G[1]},{G[4],G[3]},{G[6],G[5]},{G[8],G[7]},{G[10],G[9]}};
    const v2f WB[6] = {{G[1],G[0]},{G[3],G[2]},{G[5],G[4]},{G[7],G[6]},{G[9],G[8]},{0.f,G[10]}};

    const int blk  = blockIdx.x;
    const int c    = blk & 63;
    const int tile = (blk >> 6) & 7;
    const int b    = blk >> 9;

    const int out0  = (tile * 182) >> 3;
    const int out1  = ((tile + 1) * 182) >> 3;
    const int n_out = out1 - out0;              // 22 or 23

    const int t    = threadIdx.x;
    const int half = (t >= 96) ? 1 : 0;
    const int u    = half ? (t - 96) : t;
    const int cu   = 2 * u;
    const bool act = (u <= 90);

    const float* xp  = x  + ((size_t)(b * 64 + c)) * HW * HW + (size_t)out0 * HW + t;
    const float* fp0 = xf + ((size_t)(b * 3 + 0)) * HW * HW + (size_t)out0 * HW + t;
    const float* fp1 = fp0 + HW * HW;
    const float* fp2 = fp1 + HW * HW;

    const float* mp = muf    + (size_t)(b * 3) * NPIX + (size_t)(out0 + half) * OW + cu;
    const float* cp = sigc2f + (size_t)(b * 3) * NPIX + (size_t)(out0 + half) * OW + cu;

    __shared__ float eb[4][5][192];
    __shared__ float red[3][3];

    v2f P01[10], P23[10];
    float P4[10];
#pragma unroll
    for (int j = 0; j < 10; ++j) { P01[j] = (v2f){0.f,0.f}; P23[j] = (v2f){0.f,0.f}; P4[j] = 0.f; }

    v2f A0 = {0.f,0.f}, A1 = {0.f,0.f}, A2 = {0.f,0.f};

    v2f eE01, eE23; float eE4;

    auto vstep = [&](float xv, float a0, float a1, float a2, bool emit) {
        v2f v01 = {xv, xv * xv};
        v2f v23 = {xv * a0, xv * a1};
        float v4 = xv * a2;
        if (emit) {
            eE01 = vfma(G[10], v01, P01[0]);
            eE23 = vfma(G[10], v23, P23[0]);
            eE4  = fmaf(G[10], v4, P4[0]);
        }
#pragma unroll
        for (int j = 0; j < 9; ++j) {
            P01[j] = vfma(G[9 - j], v01, P01[j + 1]);
            P23[j] = vfma(G[9 - j], v23, P23[j + 1]);
            P4[j]  = fmaf(G[9 - j], v4, P4[j + 1]);
        }
        P01[9] = G[0] * v01;
        P23[9] = G[0] * v23;
        P4[9]  = G[0] * v4;
    };

    auto ssim2 = [&](const v2f mux, const v2f mux2, const v2f sigc,
                     const v2f mf, const v2f cc, const v2f h, v2f& A) {
        v2f t1  = mf * mux;
        v2f sfx = h - t1;
        v2f v1s = vfma(2.f, sfx, (v2f){SSIM_C2, SSIM_C2});
        v2f n1  = vfma(2.f, t1, (v2f){SSIM_C1, SSIM_C1});
        v2f num = n1 * v1s;
        v2f qd  = vfma2(mf, mf, (v2f){SSIM_C1, SSIM_C1});
        v2f den = (qd + mux2) * (cc + sigc);
        v2f inv = {__builtin_amdgcn_rcpf(den.x), __builtin_amdgcn_rcpf(den.y)};
        A = vfma2(num, inv, A);
    };

    auto store_e = [&](int slot) {
        eb[slot][0][t] = eE01.x; eb[slot][1][t] = eE01.y;
        eb[slot][2][t] = eE23.x; eb[slot][3][t] = eE23.y;
        eb[slot][4][t] = eE4;
    };

    // ---- prologue: rows 0..9, no emission ----
#pragma unroll 1
    for (int r = 0; r < 10; r += 2) {
        float xA0 = xp[0],  a00 = fp0[0],  a10 = fp1[0],  a20 = fp2[0];
        float xB0 = xp[HW], b00 = fp0[HW], b10 = fp1[HW], b20 = fp2[HW];
        xp += 2 * HW; fp0 += 2 * HW; fp1 += 2 * HW; fp2 += 2 * HW;
        vstep(xA0, a00, a10, a20, false);
        vstep(xB0, b00, b10, b20, false);
    }

    const int n_pair = n_out >> 1;   // 11

    // ---- preload pair 0 ----
    float xA = xp[0],  aA0 = fp0[0],  aA1 = fp1[0],  aA2 = fp2[0];
    float xB = xp[HW], aB0 = fp0[HW], aB1 = fp1[HW], aB2 = fp2[HW];
    xp += 2 * HW; fp0 += 2 * HW; fp1 += 2 * HW; fp2 += 2 * HW;

    // ---- main loop: 2 emit rows per iteration, prefetch next pair ----
#pragma unroll 1
    for (int p = 0; p < n_pair; ++p) {
        // prefetch next pair's stream rows (clamped; for odd n_out the last
        // prefetch leaves the tail row in xA/aA*)
        const int rb = 2 * (p + 1);
        const int r1 = (rb     < n_out) ? rb     : (n_out - 1);
        const int r2 = (rb + 1 < n_out) ? rb + 1 : (n_out - 1);
        const int o1 = (r1 - rb) * HW, o2 = (r2 - rb - 1) * HW + HW;
        const float nxA = xp[o1], nA0 = fp0[o1], nA1 = fp1[o1], nA2 = fp2[o1];
        const float nxB = xp[o2], nB0 = fp0[o2], nB1 = fp1[o2], nB2 = fp2[o2];
        xp += 2 * HW; fp0 += 2 * HW; fp1 += 2 * HW; fp2 += 2 * HW;

        v2f mf0, mf1, mf2, cc0, cc1, cc2;
        if (act) {   // moments for this thread's h-row (row 2p+half)
            mf0 = *(const v2f*)(mp);
            mf1 = *(const v2f*)(mp + NPIX);
            mf2 = *(const v2f*)(mp + 2 * NPIX);
            cc0 = *(const v2f*)(cp);
            cc1 = *(const v2f*)(cp + NPIX);
            cc2 = *(const v2f*)(cp + 2 * NPIX);
            mp += 2 * OW; cp += 2 * OW;
        }

        const int e = 2 * p;
        const int sA = e & 3, sB = (e + 1) & 3;
        vstep(xA, aA0, aA1, aA2, true);  store_e(sA);
        vstep(xB, aB0, aB1, aB2, true);  store_e(sB);
        BAR_LDS();

        xA = nxA; aA0 = nA0; aA1 = nA1; aA2 = nA2;
        xB = nxB; aB0 = nB0; aB1 = nB1; aB2 = nB2;

        if (act) {
            const int sH = half ? sB : sA;
            v2f hacc[5];
#pragma unroll
            for (int f = 0; f < 5; ++f) {
                const float* ep = &eb[sH][f][cu];
                v2f a = {0.f, 0.f};
#pragma unroll
                for (int m = 0; m < 6; ++m) {
                    v2f rd = *(const v2f*)(ep + 2 * m);
                    a = vfma2(WA[m], __builtin_shufflevector(rd, rd, 0, 0), a);
                    a = vfma2(WB[m], __builtin_shufflevector(rd, rd, 1, 1), a);
                }
                hacc[f] = a;
            }
            const v2f mux  = hacc[0];
            const v2f mux2 = mux * mux;
            const v2f sigc = hacc[1] - mux2;
            ssim2(mux, mux2, sigc, mf0, cc0, hacc[2], A0);
            ssim2(mux, mux2, sigc, mf1, cc1, hacc[3], A1);
            ssim2(mux, mux2, sigc, mf2, cc2, hacc[4], A2);
        }
    }

    // ---- odd tail row (n_out = 23): data already in xA/aA* ----
    if (n_out & 1) {
        const int e = n_out - 1;
        vstep(xA, aA0, aA1, aA2, true);
        const int sA = e & 3;
        store_e(sA);
        BAR_LDS();
        if (act && half == 0) {
            v2f mf0 = *(const v2f*)(mp);
            v2f mf1 = *(const v2f*)(mp + NPIX);
            v2f mf2 = *(const v2f*)(mp + 2 * NPIX);
            v2f cc0 = *(const v2f*)(cp);
            v2f cc1 = *(const v2f*)(cp + NPIX);
            v2f cc2 = *(const v2f*)(cp + 2 * NPIX);
            v2f hacc[5];
#pragma unroll
            for (int f = 0; f < 5; ++f) {
                const float* ep = &eb[sA][f][cu];
                v2f a = {0.f, 0.f};
#pragma unroll
                for (int m = 0; m < 6; ++m) {
                    v2f rd = *(const v2f*)(ep + 2 * m);
                    a = vfma2(WA[m], __builtin_shufflevector(rd, rd, 0, 0), a);
                    a = vfma2(WB[m], __builtin_shufflevector(rd, rd, 1, 1), a);
                }
                hacc[f] = a;
            }
            const v2f mux  = hacc[0];
            const v2f mux2 = mux * mux;
            const v2f sigc = hacc[1] - mux2;
            ssim2(mux, mux2, sigc, mf0, cc0, hacc[2], A0);
            ssim2(mux, mux2, sigc, mf1, cc1, hacc[3], A1);
            ssim2(mux, mux2, sigc, mf2, cc2, hacc[4], A2);
        }
    }

    // ---- block reduction (3 waves) ----
    float acc0 = A0.x + A0.y;
    float acc1 = A1.x + A1.y;
    float acc2 = A2.x + A2.y;
#pragma unroll
    for (int off = 32; off > 0; off >>= 1) {
        acc0 += __shfl_down(acc0, off);
        acc1 += __shfl_down(acc1, off);
        acc2 += __shfl_down(acc2, off);
    }
    const int wid = t >> 6, lane = t & 63;
    if (lane == 0) { red[0][wid] = acc0; red[1][wid] = acc1; red[2][wid] = acc2; }
    __syncthreads();
    if (t == 0) {
        const size_t o = (size_t)tile * 1536 + (size_t)b * 192;
        part[o +   0 + c] = red[0][0] + red[0][1] + red[0][2];
        part[o +  64 + c] = red[1][0] + red[1][1] + red[1][2];
        part[o + 128 + c] = red[2][0] + red[2][1] + red[2][2];
    }
}

// ---------------------------------------------------------------------------
// Kernel 3: combine tile partials -> ssim_info, then conv gate + MLP + sigmoid
// ---------------------------------------------------------------------------
__global__ __launch_bounds__(64) void gate_kernel(const float* __restrict__ part,
                                                  const float* __restrict__ sw,
                                                  const float* __restrict__ W1,
                                                  const float* __restrict__ b1,
                                                  const float* __restrict__ W2,
                                                  const float* __restrict__ b2,
                                                  float* __restrict__ out,
                                                  float* __restrict__ out_ssim) {
    const int b = blockIdx.x;
    const int c = threadIdx.x;   // 0..63

    __shared__ float s[3][64];
    __shared__ float h0[64];
    __shared__ float h1[64];

    const float inv = 1.f / (float)NPIX;
#pragma unroll
    for (int f = 0; f < 3; ++f) {
        const int i = b * 192 + f * 64 + c;
        float v = 0.f;
#pragma unroll
        for (int k = 0; k < NTILE; ++k) v += part[i + k * 1536];
        v *= inv;
        s[f][c] = v;
        out_ssim[i] = v;
    }
    __syncthreads();

    float a = 0.f;
#pragma unroll
    for (int f = 0; f < 3; ++f)
#pragma unroll
        for (int i = 0; i < 3; ++i) {
            int cc = c - 1 + i;
            if (cc >= 0 && cc < 64) a += sw[f * 3 + i] * s[f][cc];
        }
    h0[c] = fmaxf(a, 0.f);
    __syncthreads();

    float a1 = b1[c];
    for (int j = 0; j < 64; ++j) a1 += W1[c * 64 + j] * h0[j];
    h1[c] = fmaxf(a1, 0.f);
    __syncthreads();

    float a2 = b2[c];
    for (int j = 0; j < 64; ++j) a2 += W2[c * 64 + j] * h1[j];
    out[b * 64 + c] = 1.f / (1.f + expf(-a2));
}

// ---------------------------------------------------------------------------
extern "C" void kernel_launch(void* const* d_in, const int* in_sizes, int n_in,
                              void* d_out, int out_size, void* d_ws, size_t ws_size,
                              hipStream_t stream) {
    const float* x  = (const float*)d_in[0];
    const float* xf = (const float*)d_in[1];
    const float* sw = (const float*)d_in[2];
    const float* W1 = (const float*)d_in[3];
    const float* b1 = (const float*)d_in[4];
    const float* W2 = (const float*)d_in[5];
    const float* b2 = (const float*)d_in[6];
    float* out = (float*)d_out;

    float* muf  = (float*)d_ws;            // [24][182*182]
    float* sigf = muf + 24 * NPIX;         // [24][182*182]  (sig + C2)
    float* part = sigf + 24 * NPIX;        // [NTILE][8][3][64]

    muf_kernel <<<24 * 14,        256, 0, stream>>>(xf, muf, sigf);
    ssim_kernel<<<8 * 64 * NTILE, 192, 0, stream>>>(x, xf, muf, sigf, part);
    gate_kernel<<<8,               64, 0, stream>>>(part, sw, W1, b1, W2, b2, out, out + 512);
}